// Round 4
// baseline (405.204 us; speedup 1.0000x reference)
//
#include <hip/hip_runtime.h>
#include <math.h>

#define Bn 2048
#define Sn 277
#define Rn 80
#define Ln 12
#define Zn 56
#define NROWS (Bn * Sn)                   // 567296
#define ROWS_PER_BLK 64
#define NBLK_BCE (NROWS / ROWS_PER_BLK)   // 8864 exactly
#define NMOM 8
#define NBLK_TOT (NBLK_BCE + NMOM)
#define NWAVE_BCE (NBLK_BCE * 4)          // 35456

// ws layout (bytes):
//   [0,      1280)   u32  cmask_sw[80][4]  per-(rule,lane) 20-bit mask (setup)
//   [1280, 143104)   float bce_partial[35456]   (fully written, no zeroing)
//   [143104,155648)  float var_g[3136]     (atomicAdd -> memset 0)
//   [155648,155872)  float avg_g[56]       (atomicAdd -> memset 0)
#define WS_CM  0
#define WS_BCE 1280
#define WS_VAR 143104
#define WS_AVG 155648

__device__ __forceinline__ float qsum4(float v) {
    // butterfly sum within each 4-lane quad via DPP quad_perm (no DS ops)
    int t = __builtin_amdgcn_update_dpp(0, __float_as_int(v), 0xB1, 0xF, 0xF, true); // [1,0,3,2]
    v += __int_as_float(t);
    t = __builtin_amdgcn_update_dpp(0, __float_as_int(v), 0x4E, 0xF, 0xF, true);     // [2,3,0,1]
    v += __int_as_float(t);
    return v;
}

__global__ __launch_bounds__(256) void setup_kernel(
    const float* __restrict__ masks, const int* __restrict__ lhs, char* __restrict__ ws)
{
    unsigned* cmask_sw = (unsigned*)(ws + WS_CM);
    for (int idx = threadIdx.x; idx < Rn * 4; idx += 256) {
        const int r = idx >> 2, c = idx & 3;
        const int l = lhs[r];
        unsigned bits = 0u;
        for (int k = 0; k < 5; ++k)
            for (int comp = 0; comp < 4; ++comp) {
                const int j = 16 * k + 4 * c + comp;
                if (masks[l * Rn + j] > 0.5f) bits |= (1u << (4 * k + comp));
            }
        cmask_sw[idx] = bits;
    }
}

__global__ __launch_bounds__(256) void main_kernel(
    const float* __restrict__ x, const float* __restrict__ recon,
    const float* __restrict__ mu, char* __restrict__ ws)
{
    const int tid = threadIdx.x;

    if (blockIdx.x < NMOM) {
        // ---------------- moments: 8 blocks x 256 mu-rows ----------------
        float* var_g = (float*)(ws + WS_VAR);
        float* avg_g = (float*)(ws + WS_AVG);
        __shared__ float sm[32 * Zn];   // 7168 B

        const int m = blockIdx.x;
        float acc[13];
        #pragma unroll
        for (int k = 0; k < 13; ++k) acc[k] = 0.0f;
        float asum = 0.0f;

        for (int ch = 0; ch < 8; ++ch) {
            __syncthreads();
            const float* src = mu + ((size_t)m * 256 + ch * 32) * Zn;
            #pragma unroll
            for (int i = 0; i < 7; ++i) sm[tid + 256 * i] = src[tid + 256 * i];
            __syncthreads();

            #pragma unroll
            for (int k = 0; k < 13; ++k) {
                const int p = tid + 256 * k;
                if (p < Zn * Zn) {
                    const int i = p / Zn, j = p - i * Zn;
                    float a = 0.0f;
                    #pragma unroll 8
                    for (int r = 0; r < 32; ++r) a = fmaf(sm[r * Zn + i], sm[r * Zn + j], a);
                    acc[k] += a;
                }
            }
            if (tid < Zn) {
                float s = 0.0f;
                #pragma unroll 8
                for (int r = 0; r < 32; ++r) s += sm[r * Zn + tid];
                asum += s;
            }
        }
        #pragma unroll
        for (int k = 0; k < 13; ++k) {
            const int p = tid + 256 * k;
            if (p < Zn * Zn) atomicAdd(&var_g[p], acc[k]);
        }
        if (tid < Zn) atomicAdd(&avg_g[tid], asum);
        return;
    }

    // ---------------- BCE: zero-barrier, zero-LDS, one memory epoch ----------
    const int bid = blockIdx.x - NMOM;
    const unsigned* cmask_sw = (const unsigned*)(ws + WS_CM);
    float* bce_partial = (float*)(ws + WS_BCE);

    const int lrow = tid >> 2;          // 0..63
    const int c = tid & 3;              // lane within row-quad
    const size_t row = (size_t)bid * ROWS_PER_BLK + lrow;
    const float4* xp = (const float4*)(x + row * Rn);
    const float4* rp = (const float4*)(recon + row * Rn);

    // all 10 independent loads up front
    const float4 xv0 = xp[c];
    const float4 xv1 = xp[c + 4];
    const float4 xv2 = xp[c + 8];
    const float4 xv3 = xp[c + 12];
    const float4 xv4 = xp[c + 16];
    const float4 rv0 = rp[c];
    const float4 rv1 = rp[c + 4];
    const float4 rv2 = rp[c + 8];
    const float4 rv3 = rp[c + 12];
    const float4 rv4 = rp[c + 16];

    // argmax via dot with index weights (x is exactly one-hot)
    auto dotc = [](const float4 v, float base) {
        return fmaf(v.x, base, fmaf(v.y, base + 1.f, fmaf(v.z, base + 2.f, v.w * (base + 3.f))));
    };
    float dl = dotc(xv0, 0.f) + dotc(xv1, 16.f) + dotc(xv2, 32.f)
             + dotc(xv3, 48.f) + dotc(xv4, 64.f);
    const float xs = ((xv0.x + xv0.y) + (xv0.z + xv0.w)) + ((xv1.x + xv1.y) + (xv1.z + xv1.w))
                   + ((xv2.x + xv2.y) + (xv2.z + xv2.w)) + ((xv3.x + xv3.y) + (xv3.z + xv3.w))
                   + ((xv4.x + xv4.y) + (xv4.z + xv4.w));
    dl = fmaf((float)(4 * c), xs, dl);
    const int amax = (int)(qsum4(dl) + 0.5f);

    // one L1-hot dword: this lane's 20 mask bits for the winning rule
    const unsigned bits = cmask_sw[(amax << 2) | c];

    auto mskd = [&](float4 v, int k) -> float4 {
        float4 r;
        r.x = ((bits >> (4 * k + 0)) & 1u) ? v.x : 0.f;
        r.y = ((bits >> (4 * k + 1)) & 1u) ? v.y : 0.f;
        r.z = ((bits >> (4 * k + 2)) & 1u) ? v.z : 0.f;
        r.w = ((bits >> (4 * k + 3)) & 1u) ? v.w : 0.f;
        return r;
    };
    const float4 m0 = mskd(rv0, 0);
    const float4 m1 = mskd(rv1, 1);
    const float4 m2 = mskd(rv2, 2);
    const float4 m3 = mskd(rv3, 3);
    const float4 m4 = mskd(rv4, 4);

    float dd = ((m0.x + m0.y) + (m0.z + m0.w)) + ((m1.x + m1.y) + (m1.z + m1.w))
             + ((m2.x + m2.y) + (m2.z + m2.w)) + ((m3.x + m3.y) + (m3.z + m3.w))
             + ((m4.x + m4.y) + (m4.z + m4.w));
    const float invd = __builtin_amdgcn_rcpf(qsum4(dd));

    const int ka = amax >> 4;           // owning chunk 0..4
    const int ca = (amax >> 2) & 3;     // owning lane
    const int comp = amax & 3;
    const bool owner = (c == ca);

    float ss = 0.0f;
    float ta = 1.0f;
    auto acc = [&](const float4 m, int k) {
        const float t0 = fminf(m.x * invd, 1.f);
        const float t1 = fminf(m.y * invd, 1.f);
        const float t2 = fminf(m.z * invd, 1.f);
        const float t3 = fminf(m.w * invd, 1.f);
        ss += fmaxf(__logf(1.f - t0), -100.f) + fmaxf(__logf(1.f - t1), -100.f)
            + fmaxf(__logf(1.f - t2), -100.f) + fmaxf(__logf(1.f - t3), -100.f);
        if (owner && k == ka)
            ta = (comp == 0) ? t0 : (comp == 1) ? t1 : (comp == 2) ? t2 : t3;
    };
    acc(m0, 0); acc(m1, 1); acc(m2, 2); acc(m3, 3); acc(m4, 4);
    if (owner)
        ss += fmaxf(__logf(ta), -100.f) - fmaxf(__logf(1.f - ta), -100.f);

    // wave reduction: quad DPP + 4 shuffles, then one float store per wave
    ss = qsum4(ss);
    ss += __shfl_xor(ss, 4);
    ss += __shfl_xor(ss, 8);
    ss += __shfl_xor(ss, 16);
    ss += __shfl_xor(ss, 32);
    if ((tid & 63) == 0)
        bce_partial[bid * 4 + (tid >> 6)] = ss;
}

__global__ __launch_bounds__(256) void finalize_kernel(
    const char* __restrict__ ws, float* __restrict__ out)
{
    const float* bce_partial = (const float*)(ws + WS_BCE);
    const float* var_g = (const float*)(ws + WS_VAR);
    const float* avg_g = (const float*)(ws + WS_AVG);
    __shared__ double sb[4];
    __shared__ float sv[4], sa[4];
    const int tid = threadIdx.x;

    double bsum = 0.0;
    for (int i = tid; i < NWAVE_BCE; i += 256) bsum += (double)bce_partial[i];

    float vsum = 0.0f;
    for (int p = tid; p < Zn * Zn; p += 256) {
        const int i = p / Zn, j = p - i * Zn;
        const float e = var_g[p] * (1.0f / (float)Bn) - ((i == j) ? 1.0f : 0.0f);
        vsum += fabsf(e);
    }
    float asum = 0.0f;
    for (int z = tid; z < Zn; z += 256) { const float a = avg_g[z]; asum += a * a; }

    #pragma unroll
    for (int o = 32; o; o >>= 1) {
        bsum += __shfl_xor(bsum, o);
        vsum += __shfl_xor(vsum, o);
        asum += __shfl_xor(asum, o);
    }
    if ((tid & 63) == 0) { const int w = tid >> 6; sb[w] = bsum; sv[w] = vsum; sa[w] = asum; }
    __syncthreads();
    if (tid == 0) {
        const double tb = (sb[0] + sb[1]) + (sb[2] + sb[3]);
        const double tv = (double)((sv[0] + sv[1]) + (sv[2] + sv[3]));
        const double ta = (double)((sa[0] + sa[1]) + (sa[2] + sa[3]));
        const double bce = -tb / ((double)Sn * (double)Bn);
        const double mom = ta / ((double)Bn * (double)Bn * (double)Zn)
                         + tv / ((double)Zn * (double)Zn);
        out[0] = (float)(bce + mom);
    }
}

extern "C" void kernel_launch(void* const* d_in, const int* in_sizes, int n_in,
                              void* d_out, int out_size, void* d_ws, size_t ws_size,
                              hipStream_t stream)
{
    const float* x     = (const float*)d_in[0];
    const float* recon = (const float*)d_in[1];
    const float* mu    = (const float*)d_in[2];
    // d_in[3] = log_var: unused by the reference
    const float* masks = (const float*)d_in[4];
    const int*   lhs   = (const int*)d_in[5];
    float* out = (float*)d_out;
    char* ws = (char*)d_ws;

    hipMemsetAsync(ws + WS_VAR, 0, 12544 + 224, stream);   // atomic accumulators only
    setup_kernel<<<1, 256, 0, stream>>>(masks, lhs, ws);
    main_kernel<<<NBLK_TOT, 256, 0, stream>>>(x, recon, mu, ws);
    finalize_kernel<<<1, 256, 0, stream>>>(ws, out);
}

// Round 5
// 397.270 us; speedup vs baseline: 1.0200x; 1.0200x over previous
//
#include <hip/hip_runtime.h>
#include <math.h>

#define Bn 2048
#define Sn 277
#define Rn 80
#define Ln 12
#define Zn 56
#define NROWS (Bn * Sn)                   // 567296
#define ROWS_PER_BLK 64
#define NBLK_BCE (NROWS / ROWS_PER_BLK)   // 8864 exactly
#define NMOM 8
#define NBLK_TOT (NBLK_BCE + NMOM)
#define NWAVE_BCE (NBLK_BCE * 4)          // 35456

// ws layout (bytes):
//   [0,      1280)   u32  cmask_sw[80][4]  per-(rule,lane) 20-bit mask (setup)
//   [1280, 143104)   float bce_partial[35456]   (fully written, no zeroing)
//   [143104,155648)  float var_g[3136]     (atomicAdd -> memset 0)
//   [155648,155872)  float avg_g[56]       (atomicAdd -> memset 0)
#define WS_CM  0
#define WS_BCE 1280
#define WS_VAR 143104
#define WS_AVG 155648

__device__ __forceinline__ float qsum4(float v) {
    // butterfly sum within each 4-lane quad via DPP quad_perm (no DS ops)
    int t = __builtin_amdgcn_update_dpp(0, __float_as_int(v), 0xB1, 0xF, 0xF, true); // [1,0,3,2]
    v += __int_as_float(t);
    t = __builtin_amdgcn_update_dpp(0, __float_as_int(v), 0x4E, 0xF, 0xF, true);     // [2,3,0,1]
    v += __int_as_float(t);
    return v;
}

__global__ __launch_bounds__(256) void setup_kernel(
    const float* __restrict__ masks, const int* __restrict__ lhs, char* __restrict__ ws)
{
    unsigned* cmask_sw = (unsigned*)(ws + WS_CM);
    for (int idx = threadIdx.x; idx < Rn * 4; idx += 256) {
        const int r = idx >> 2, c = idx & 3;
        const int l = lhs[r];
        unsigned bits = 0u;
        for (int k = 0; k < 5; ++k)
            for (int comp = 0; comp < 4; ++comp) {
                const int j = 16 * k + 4 * c + comp;
                if (masks[l * Rn + j] > 0.5f) bits |= (1u << (4 * k + comp));
            }
        cmask_sw[idx] = bits;
    }
}

// min-waves/EU = 4 -> VGPR budget 128: enough to keep all 10 float4 loads in
// flight (40 result VGPRs). Default bounds gave VGPR_Count=36 -> serialized
// loads, ~600 cy wait per load (rounds 1-4 all latency-bound at ~122-203 us).
__global__ __launch_bounds__(256, 4) void main_kernel(
    const float* __restrict__ x, const float* __restrict__ recon,
    const float* __restrict__ mu, char* __restrict__ ws)
{
    const int tid = threadIdx.x;

    if (blockIdx.x < NMOM) {
        // ---------------- moments: 8 blocks x 256 mu-rows ----------------
        float* var_g = (float*)(ws + WS_VAR);
        float* avg_g = (float*)(ws + WS_AVG);
        __shared__ float sm[32 * Zn];   // 7168 B

        const int m = blockIdx.x;
        float acc[13];
        #pragma unroll
        for (int k = 0; k < 13; ++k) acc[k] = 0.0f;
        float asum = 0.0f;

        for (int ch = 0; ch < 8; ++ch) {
            __syncthreads();
            const float* src = mu + ((size_t)m * 256 + ch * 32) * Zn;
            #pragma unroll
            for (int i = 0; i < 7; ++i) sm[tid + 256 * i] = src[tid + 256 * i];
            __syncthreads();

            #pragma unroll
            for (int k = 0; k < 13; ++k) {
                const int p = tid + 256 * k;
                if (p < Zn * Zn) {
                    const int i = p / Zn, j = p - i * Zn;
                    float a = 0.0f;
                    #pragma unroll 8
                    for (int r = 0; r < 32; ++r) a = fmaf(sm[r * Zn + i], sm[r * Zn + j], a);
                    acc[k] += a;
                }
            }
            if (tid < Zn) {
                float s = 0.0f;
                #pragma unroll 8
                for (int r = 0; r < 32; ++r) s += sm[r * Zn + tid];
                asum += s;
            }
        }
        #pragma unroll
        for (int k = 0; k < 13; ++k) {
            const int p = tid + 256 * k;
            if (p < Zn * Zn) atomicAdd(&var_g[p], acc[k]);
        }
        if (tid < Zn) atomicAdd(&avg_g[tid], asum);
        return;
    }

    // ---------------- BCE: zero-barrier, zero-LDS, one memory epoch ----------
    const int bid = blockIdx.x - NMOM;
    const unsigned* cmask_sw = (const unsigned*)(ws + WS_CM);
    float* bce_partial = (float*)(ws + WS_BCE);

    const int lrow = tid >> 2;          // 0..63
    const int c = tid & 3;              // lane within row-quad
    const size_t row = (size_t)bid * ROWS_PER_BLK + lrow;
    const float4* xp = (const float4*)(x + row * Rn);
    const float4* rp = (const float4*)(recon + row * Rn);

    // all 10 independent loads; x first (argmax consumes them while recon flies)
    const float4 xv0 = xp[c];
    const float4 xv1 = xp[c + 4];
    const float4 xv2 = xp[c + 8];
    const float4 xv3 = xp[c + 12];
    const float4 xv4 = xp[c + 16];
    const float4 rv0 = rp[c];
    const float4 rv1 = rp[c + 4];
    const float4 rv2 = rp[c + 8];
    const float4 rv3 = rp[c + 12];
    const float4 rv4 = rp[c + 16];

    // argmax via dot with index weights (x is exactly one-hot)
    auto dotc = [](const float4 v, float base) {
        return fmaf(v.x, base, fmaf(v.y, base + 1.f, fmaf(v.z, base + 2.f, v.w * (base + 3.f))));
    };
    float dl = dotc(xv0, 0.f) + dotc(xv1, 16.f) + dotc(xv2, 32.f)
             + dotc(xv3, 48.f) + dotc(xv4, 64.f);
    const float xs = ((xv0.x + xv0.y) + (xv0.z + xv0.w)) + ((xv1.x + xv1.y) + (xv1.z + xv1.w))
                   + ((xv2.x + xv2.y) + (xv2.z + xv2.w)) + ((xv3.x + xv3.y) + (xv3.z + xv3.w))
                   + ((xv4.x + xv4.y) + (xv4.z + xv4.w));
    dl = fmaf((float)(4 * c), xs, dl);
    const int amax = (int)(qsum4(dl) + 0.5f);

    // one L1-hot dword: this lane's 20 mask bits for the winning rule
    const unsigned bits = cmask_sw[(amax << 2) | c];

    auto mskd = [&](float4 v, int k) -> float4 {
        float4 r;
        r.x = ((bits >> (4 * k + 0)) & 1u) ? v.x : 0.f;
        r.y = ((bits >> (4 * k + 1)) & 1u) ? v.y : 0.f;
        r.z = ((bits >> (4 * k + 2)) & 1u) ? v.z : 0.f;
        r.w = ((bits >> (4 * k + 3)) & 1u) ? v.w : 0.f;
        return r;
    };
    const float4 m0 = mskd(rv0, 0);
    const float4 m1 = mskd(rv1, 1);
    const float4 m2 = mskd(rv2, 2);
    const float4 m3 = mskd(rv3, 3);
    const float4 m4 = mskd(rv4, 4);

    float dd = ((m0.x + m0.y) + (m0.z + m0.w)) + ((m1.x + m1.y) + (m1.z + m1.w))
             + ((m2.x + m2.y) + (m2.z + m2.w)) + ((m3.x + m3.y) + (m3.z + m3.w))
             + ((m4.x + m4.y) + (m4.z + m4.w));
    const float invd = __builtin_amdgcn_rcpf(qsum4(dd));

    const int ka = amax >> 4;           // owning chunk 0..4
    const int ca = (amax >> 2) & 3;     // owning lane
    const int comp = amax & 3;
    const bool owner = (c == ca);

    // Product trick: sum(log(1-t_i)) = log(prod(1-t_i)). At most one t_i > 0.5
    // per row, so the 20-factor product cannot underflow unless a factor is
    // exactly 0 (t==1 exactly) -> guarded fallback reproduces the per-element
    // clamp semantics bit-exactly. Cuts 20 v_log_f32 per thread to 1.
    float p = 1.0f;
    float ta = 1.0f;
    float om[20];   // 1-t values, kept for the (never-taken) fallback
    auto accp = [&](const float4 m, int k) {
        const float t0 = fminf(m.x * invd, 1.f);
        const float t1 = fminf(m.y * invd, 1.f);
        const float t2 = fminf(m.z * invd, 1.f);
        const float t3 = fminf(m.w * invd, 1.f);
        const float o0 = 1.f - t0, o1 = 1.f - t1, o2 = 1.f - t2, o3 = 1.f - t3;
        om[4 * k + 0] = o0; om[4 * k + 1] = o1; om[4 * k + 2] = o2; om[4 * k + 3] = o3;
        p *= (o0 * o1) * (o2 * o3);
        if (owner && k == ka)
            ta = (comp == 0) ? t0 : (comp == 1) ? t1 : (comp == 2) ? t2 : t3;
    };
    accp(m0, 0); accp(m1, 1); accp(m2, 2); accp(m3, 3); accp(m4, 4);

    float ss;
    if (p > 0.0f) {
        ss = __builtin_amdgcn_logf(p) * 0.69314718055994531f;   // log2 -> ln
    } else {
        ss = 0.0f;
        #pragma unroll
        for (int i = 0; i < 20; ++i)
            ss += fmaxf(__logf(om[i]), -100.f);
    }
    if (owner)
        ss += fmaxf(__logf(ta), -100.f) - fmaxf(__logf(1.f - ta), -100.f);

    // wave reduction: quad DPP + 4 shuffles, then one float store per wave
    ss = qsum4(ss);
    ss += __shfl_xor(ss, 4);
    ss += __shfl_xor(ss, 8);
    ss += __shfl_xor(ss, 16);
    ss += __shfl_xor(ss, 32);
    if ((tid & 63) == 0)
        bce_partial[bid * 4 + (tid >> 6)] = ss;
}

__global__ __launch_bounds__(256) void finalize_kernel(
    const char* __restrict__ ws, float* __restrict__ out)
{
    const float* bce_partial = (const float*)(ws + WS_BCE);
    const float* var_g = (const float*)(ws + WS_VAR);
    const float* avg_g = (const float*)(ws + WS_AVG);
    __shared__ double sb[4];
    __shared__ float sv[4], sa[4];
    const int tid = threadIdx.x;

    double bsum = 0.0;
    for (int i = tid; i < NWAVE_BCE; i += 256) bsum += (double)bce_partial[i];

    float vsum = 0.0f;
    for (int p = tid; p < Zn * Zn; p += 256) {
        const int i = p / Zn, j = p - i * Zn;
        const float e = var_g[p] * (1.0f / (float)Bn) - ((i == j) ? 1.0f : 0.0f);
        vsum += fabsf(e);
    }
    float asum = 0.0f;
    for (int z = tid; z < Zn; z += 256) { const float a = avg_g[z]; asum += a * a; }

    #pragma unroll
    for (int o = 32; o; o >>= 1) {
        bsum += __shfl_xor(bsum, o);
        vsum += __shfl_xor(vsum, o);
        asum += __shfl_xor(asum, o);
    }
    if ((tid & 63) == 0) { const int w = tid >> 6; sb[w] = bsum; sv[w] = vsum; sa[w] = asum; }
    __syncthreads();
    if (tid == 0) {
        const double tb = (sb[0] + sb[1]) + (sb[2] + sb[3]);
        const double tv = (double)((sv[0] + sv[1]) + (sv[2] + sv[3]));
        const double ta = (double)((sa[0] + sa[1]) + (sa[2] + sa[3]));
        const double bce = -tb / ((double)Sn * (double)Bn);
        const double mom = ta / ((double)Bn * (double)Bn * (double)Zn)
                         + tv / ((double)Zn * (double)Zn);
        out[0] = (float)(bce + mom);
    }
}

extern "C" void kernel_launch(void* const* d_in, const int* in_sizes, int n_in,
                              void* d_out, int out_size, void* d_ws, size_t ws_size,
                              hipStream_t stream)
{
    const float* x     = (const float*)d_in[0];
    const float* recon = (const float*)d_in[1];
    const float* mu    = (const float*)d_in[2];
    // d_in[3] = log_var: unused by the reference
    const float* masks = (const float*)d_in[4];
    const int*   lhs   = (const int*)d_in[5];
    float* out = (float*)d_out;
    char* ws = (char*)d_ws;

    hipMemsetAsync(ws + WS_VAR, 0, 12544 + 224, stream);   // atomic accumulators only
    setup_kernel<<<1, 256, 0, stream>>>(masks, lhs, ws);
    main_kernel<<<NBLK_TOT, 256, 0, stream>>>(x, recon, mu, ws);
    finalize_kernel<<<1, 256, 0, stream>>>(ws, out);
}

// Round 6
// 381.297 us; speedup vs baseline: 1.0627x; 1.0419x over previous
//
#include <hip/hip_runtime.h>
#include <math.h>

#define Bn 2048
#define Sn 277
#define Rn 80
#define Ln 12
#define Zn 56
#define NROWS (Bn * Sn)                   // 567296
#define ROWS_PER_BLK 256
#define NBLK_BCE (NROWS / ROWS_PER_BLK)   // 2216 exactly
#define NMOM 8
#define NBLK_TOT (NBLK_BCE + NMOM)
#define NWAVE_BCE (NBLK_BCE * 4)          // 8864

// ws layout (bytes):
//   [0,     1280)   u32  cmask_sw[80][4]  per-(rule,lane) 20-bit mask (setup)
//   [1280, 36736)   float bce_partial[8864]   (fully written, no zeroing)
//   [36736, 49280)  float var_g[3136]     (atomicAdd -> memset 0)
//   [49280, 49504)  float avg_g[56]       (atomicAdd -> memset 0)
#define WS_CM  0
#define WS_BCE 1280
#define WS_VAR 36736
#define WS_AVG 49280

__device__ __forceinline__ float qsum4(float v) {
    // butterfly sum within each 4-lane quad via DPP quad_perm (no DS ops)
    int t = __builtin_amdgcn_update_dpp(0, __float_as_int(v), 0xB1, 0xF, 0xF, true); // [1,0,3,2]
    v += __int_as_float(t);
    t = __builtin_amdgcn_update_dpp(0, __float_as_int(v), 0x4E, 0xF, 0xF, true);     // [2,3,0,1]
    v += __int_as_float(t);
    return v;
}

__global__ __launch_bounds__(256) void setup_kernel(
    const float* __restrict__ masks, const int* __restrict__ lhs, char* __restrict__ ws)
{
    unsigned* cmask_sw = (unsigned*)(ws + WS_CM);
    for (int idx = threadIdx.x; idx < Rn * 4; idx += 256) {
        const int r = idx >> 2, c = idx & 3;
        const int l = lhs[r];
        unsigned bits = 0u;
        for (int k = 0; k < 5; ++k)
            for (int comp = 0; comp < 4; ++comp) {
                const int j = 16 * k + 4 * c + comp;
                if (masks[l * Rn + j] > 0.5f) bits |= (1u << (4 * k + comp));
            }
        cmask_sw[idx] = bits;
    }
}

// (256,2): VGPR budget 256 so the 40 float4 load results (160 VGPRs) can ALL
// stay in flight. Rounds 1-5 plateaued at ~122us / 3.0 TB/s effective with
// VGPR_Count=36 -> compiler serialized loads into tiny epochs. This kernel is
// the controlled MLP experiment: 40 independent loads issued before any use,
// consumption in issue order, sched_barrier pinning loads above compute.
__global__ __launch_bounds__(256, 2) void main_kernel(
    const float* __restrict__ x, const float* __restrict__ recon,
    const float* __restrict__ mu, char* __restrict__ ws)
{
    const int tid = threadIdx.x;

    if (blockIdx.x < NMOM) {
        // ---------------- moments: 8 blocks x 256 mu-rows ----------------
        float* var_g = (float*)(ws + WS_VAR);
        float* avg_g = (float*)(ws + WS_AVG);
        __shared__ float sm[32 * Zn];   // 7168 B

        const int m = blockIdx.x;
        float acc[13];
        #pragma unroll
        for (int k = 0; k < 13; ++k) acc[k] = 0.0f;
        float asum = 0.0f;

        for (int ch = 0; ch < 8; ++ch) {
            __syncthreads();
            const float* src = mu + ((size_t)m * 256 + ch * 32) * Zn;
            #pragma unroll
            for (int i = 0; i < 7; ++i) sm[tid + 256 * i] = src[tid + 256 * i];
            __syncthreads();

            #pragma unroll
            for (int k = 0; k < 13; ++k) {
                const int p = tid + 256 * k;
                if (p < Zn * Zn) {
                    const int i = p / Zn, j = p - i * Zn;
                    float a = 0.0f;
                    #pragma unroll 8
                    for (int r = 0; r < 32; ++r) a = fmaf(sm[r * Zn + i], sm[r * Zn + j], a);
                    acc[k] += a;
                }
            }
            if (tid < Zn) {
                float s = 0.0f;
                #pragma unroll 8
                for (int r = 0; r < 32; ++r) s += sm[r * Zn + tid];
                asum += s;
            }
        }
        #pragma unroll
        for (int k = 0; k < 13; ++k) {
            const int p = tid + 256 * k;
            if (p < Zn * Zn) atomicAdd(&var_g[p], acc[k]);
        }
        if (tid < Zn) atomicAdd(&avg_g[tid], asum);
        return;
    }

    // ---------------- BCE: 4 rows/thread, 40 loads in flight ----------------
    const int bid = blockIdx.x - NMOM;
    const unsigned* cmask_sw = (const unsigned*)(ws + WS_CM);
    float* bce_partial = (float*)(ws + WS_BCE);

    const int q = tid >> 2;             // quad 0..63
    const int c = tid & 3;              // lane within quad
    const size_t row0 = (size_t)bid * ROWS_PER_BLK + 4 * (size_t)q;
    const float4* xp0 = (const float4*)(x + row0 * Rn);      // row j at +20*j float4s
    const float4* rp0 = (const float4*)(recon + row0 * Rn);

    // Issue ALL 40 independent loads: 20 x (consumed first), 20 recon (last).
    float4 X[4][5], Rv[4][5];
    #pragma unroll
    for (int j = 0; j < 4; ++j)
        #pragma unroll
        for (int k = 0; k < 5; ++k)
            X[j][k] = xp0[20 * j + c + 4 * k];
    #pragma unroll
    for (int j = 0; j < 4; ++j)
        #pragma unroll
        for (int k = 0; k < 5; ++k)
            Rv[j][k] = rp0[20 * j + c + 4 * k];
    __builtin_amdgcn_sched_barrier(0);   // keep every load issued above all compute

    auto dotc = [](const float4 v, float base) {
        return fmaf(v.x, base, fmaf(v.y, base + 1.f, fmaf(v.z, base + 2.f, v.w * (base + 3.f))));
    };

    float ss = 0.0f;
    #pragma unroll
    for (int j = 0; j < 4; ++j) {
        // argmax via dot with index weights (x is exactly one-hot)
        float dl = dotc(X[j][0], 0.f) + dotc(X[j][1], 16.f) + dotc(X[j][2], 32.f)
                 + dotc(X[j][3], 48.f) + dotc(X[j][4], 64.f);
        float xs = 0.f;
        #pragma unroll
        for (int k = 0; k < 5; ++k)
            xs += ((X[j][k].x + X[j][k].y) + (X[j][k].z + X[j][k].w));
        dl = fmaf((float)(4 * c), xs, dl);
        const int amax = (int)(qsum4(dl) + 0.5f);

        const unsigned bits = cmask_sw[(amax << 2) | c];   // L1-hot dword

        float4 M[5];
        #pragma unroll
        for (int k = 0; k < 5; ++k) {
            M[k].x = ((bits >> (4 * k + 0)) & 1u) ? Rv[j][k].x : 0.f;
            M[k].y = ((bits >> (4 * k + 1)) & 1u) ? Rv[j][k].y : 0.f;
            M[k].z = ((bits >> (4 * k + 2)) & 1u) ? Rv[j][k].z : 0.f;
            M[k].w = ((bits >> (4 * k + 3)) & 1u) ? Rv[j][k].w : 0.f;
        }
        float dd = 0.f;
        #pragma unroll
        for (int k = 0; k < 5; ++k)
            dd += ((M[k].x + M[k].y) + (M[k].z + M[k].w));
        const float invd = __builtin_amdgcn_rcpf(qsum4(dd));

        const int ka = amax >> 4;
        const int ca = (amax >> 2) & 3;
        const int comp = amax & 3;
        const bool owner = (c == ca);

        // sum(log(1-t)) = log(prod(1-t)); product can only hit 0 if some t==1
        // exactly -> guarded fallback (reloads recon) keeps clamp semantics.
        float p = 1.0f;
        float ta = 1.0f;
        #pragma unroll
        for (int k = 0; k < 5; ++k) {
            const float t0 = fminf(M[k].x * invd, 1.f);
            const float t1 = fminf(M[k].y * invd, 1.f);
            const float t2 = fminf(M[k].z * invd, 1.f);
            const float t3 = fminf(M[k].w * invd, 1.f);
            p *= ((1.f - t0) * (1.f - t1)) * ((1.f - t2) * (1.f - t3));
            if (owner && k == ka)
                ta = (comp == 0) ? t0 : (comp == 1) ? t1 : (comp == 2) ? t2 : t3;
        }
        if (p > 0.0f) {
            ss += __builtin_amdgcn_logf(p) * 0.69314718055994531f;   // log2 -> ln
        } else {
            // astronomically rare: recompute per-element with clamps (reload)
            const float4* rpj = rp0 + 20 * j;
            #pragma unroll
            for (int k = 0; k < 5; ++k) {
                const float4 v = rpj[c + 4 * k];
                const float w0 = ((bits >> (4 * k + 0)) & 1u) ? v.x : 0.f;
                const float w1 = ((bits >> (4 * k + 1)) & 1u) ? v.y : 0.f;
                const float w2 = ((bits >> (4 * k + 2)) & 1u) ? v.z : 0.f;
                const float w3 = ((bits >> (4 * k + 3)) & 1u) ? v.w : 0.f;
                ss += fmaxf(__logf(1.f - fminf(w0 * invd, 1.f)), -100.f)
                    + fmaxf(__logf(1.f - fminf(w1 * invd, 1.f)), -100.f)
                    + fmaxf(__logf(1.f - fminf(w2 * invd, 1.f)), -100.f)
                    + fmaxf(__logf(1.f - fminf(w3 * invd, 1.f)), -100.f);
            }
        }
        if (owner)
            ss += fmaxf(__logf(ta), -100.f) - fmaxf(__logf(1.f - ta), -100.f);
    }

    // wave reduction: quad DPP + 4 shuffles, one float store per wave
    ss = qsum4(ss);
    ss += __shfl_xor(ss, 4);
    ss += __shfl_xor(ss, 8);
    ss += __shfl_xor(ss, 16);
    ss += __shfl_xor(ss, 32);
    if ((tid & 63) == 0)
        bce_partial[bid * 4 + (tid >> 6)] = ss;
}

__global__ __launch_bounds__(256) void finalize_kernel(
    const char* __restrict__ ws, float* __restrict__ out)
{
    const float* bce_partial = (const float*)(ws + WS_BCE);
    const float* var_g = (const float*)(ws + WS_VAR);
    const float* avg_g = (const float*)(ws + WS_AVG);
    __shared__ double sb[4];
    __shared__ float sv[4], sa[4];
    const int tid = threadIdx.x;

    double bsum = 0.0;
    for (int i = tid; i < NWAVE_BCE; i += 256) bsum += (double)bce_partial[i];

    float vsum = 0.0f;
    for (int p = tid; p < Zn * Zn; p += 256) {
        const int i = p / Zn, j = p - i * Zn;
        const float e = var_g[p] * (1.0f / (float)Bn) - ((i == j) ? 1.0f : 0.0f);
        vsum += fabsf(e);
    }
    float asum = 0.0f;
    for (int z = tid; z < Zn; z += 256) { const float a = avg_g[z]; asum += a * a; }

    #pragma unroll
    for (int o = 32; o; o >>= 1) {
        bsum += __shfl_xor(bsum, o);
        vsum += __shfl_xor(vsum, o);
        asum += __shfl_xor(asum, o);
    }
    if ((tid & 63) == 0) { const int w = tid >> 6; sb[w] = bsum; sv[w] = vsum; sa[w] = asum; }
    __syncthreads();
    if (tid == 0) {
        const double tb = (sb[0] + sb[1]) + (sb[2] + sb[3]);
        const double tv = (double)((sv[0] + sv[1]) + (sv[2] + sv[3]));
        const double ta = (double)((sa[0] + sa[1]) + (sa[2] + sa[3]));
        const double bce = -tb / ((double)Sn * (double)Bn);
        const double mom = ta / ((double)Bn * (double)Bn * (double)Zn)
                         + tv / ((double)Zn * (double)Zn);
        out[0] = (float)(bce + mom);
    }
}

extern "C" void kernel_launch(void* const* d_in, const int* in_sizes, int n_in,
                              void* d_out, int out_size, void* d_ws, size_t ws_size,
                              hipStream_t stream)
{
    const float* x     = (const float*)d_in[0];
    const float* recon = (const float*)d_in[1];
    const float* mu    = (const float*)d_in[2];
    // d_in[3] = log_var: unused by the reference
    const float* masks = (const float*)d_in[4];
    const int*   lhs   = (const int*)d_in[5];
    float* out = (float*)d_out;
    char* ws = (char*)d_ws;

    hipMemsetAsync(ws + WS_VAR, 0, 12544 + 224, stream);   // atomic accumulators only
    setup_kernel<<<1, 256, 0, stream>>>(masks, lhs, ws);
    main_kernel<<<NBLK_TOT, 256, 0, stream>>>(x, recon, mu, ws);
    finalize_kernel<<<1, 256, 0, stream>>>(ws, out);
}